// Round 2
// baseline (200.457 us; speedup 1.0000x reference)
//
#include <hip/hip_runtime.h>

// ---- types ----
typedef __bf16 bf16x8 __attribute__((ext_vector_type(8)));
typedef float  f32x4  __attribute__((ext_vector_type(4)));

__device__ __forceinline__ short f2bf(float f) {
  union { float f; unsigned u; } v; v.f = f;
  unsigned r = v.u + 0x7fffu + ((v.u >> 16) & 1u);
  return (short)(r >> 16);
}

// async global->LDS (16B per lane); LDS dest must be wave-uniform base + lane*16
__device__ __forceinline__ void gl_lds16(const short* g, short* l) {
  __builtin_amdgcn_global_load_lds((const __attribute__((address_space(1))) void*)g,
                                   (__attribute__((address_space(3))) void*)l, 16, 0, 0);
}

// ---- cast x fp32 -> bf16 (vectorized) ----
__global__ __launch_bounds__(256) void cast_x_kernel(const float* __restrict__ in,
                                                     short* __restrict__ out, int n4) {
  int i = blockIdx.x * 256 + threadIdx.x;
  if (i >= n4) return;
  float4 f = reinterpret_cast<const float4*>(in)[i];
  short4 o;
  o.x = f2bf(f.x); o.y = f2bf(f.y); o.z = f2bf(f.z); o.w = f2bf(f.w);
  reinterpret_cast<short4*>(out)[i] = o;
}

// ---- transpose + cast: in[R][Cc] fp32 -> out[Cc][R] bf16 ----
__global__ __launch_bounds__(256) void transpose_cast(const float* __restrict__ in,
                                                      short* __restrict__ out, int R, int Cc) {
  __shared__ short tile[64][65];
  int bx = blockIdx.x * 64;
  int by = blockIdx.y * 64;
  int tx = threadIdx.x & 63, ty = threadIdx.x >> 6;
  #pragma unroll
  for (int i = ty; i < 64; i += 4)
    tile[i][tx] = f2bf(in[(size_t)(by + i) * Cc + bx + tx]);
  __syncthreads();
  #pragma unroll
  for (int i = ty; i < 64; i += 4)
    out[(size_t)(bx + i) * R + by + tx] = tile[tx][i];
}

// ---- GEMM1: qkv = x_bf[4096][1024] * Wqkv_t[3072][1024]^T + bqkv
//      q,k -> [B2][H16][T2048][D64] bf16 (q scaled 0.125); v -> TRANSPOSED [BH][D64][T2048]
__global__ __launch_bounds__(256) void gemm_qkv(const short* __restrict__ A,
                                                const short* __restrict__ Bt,
                                                const float* __restrict__ bias,
                                                short* __restrict__ qo,
                                                short* __restrict__ ko,
                                                short* __restrict__ vt) {
  const int K = 1024;
  __shared__ short Al[8192];   // linear [128][64]
  __shared__ short Bl[8192];
  int tid = threadIdx.x;
  int mtile = blockIdx.y * 128, ntile = blockIdx.x * 128;
  int w = tid >> 6, l = tid & 63;
  int wr = w >> 1, wc = w & 1;
  int lr = l & 15, lg = l >> 4;

  f32x4 zero4 = {0.f, 0.f, 0.f, 0.f};
  f32x4 acc[4][4];
  #pragma unroll
  for (int i = 0; i < 4; ++i)
    #pragma unroll
    for (int j = 0; j < 4; ++j) acc[i][j] = zero4;

  for (int k0 = 0; k0 < K; k0 += 64) {
    __syncthreads();
    #pragma unroll
    for (int c = 0; c < 4; ++c) {
      int idx = tid + c * 256;
      int row = idx >> 3, kc = idx & 7;
      gl_lds16(&A[(size_t)(mtile + row) * K + k0 + kc * 8], &Al[idx * 8]);
      gl_lds16(&Bt[(size_t)(ntile + row) * K + k0 + kc * 8], &Bl[idx * 8]);
    }
    __syncthreads();
    __builtin_amdgcn_s_setprio(1);
    #pragma unroll
    for (int kk = 0; kk < 2; ++kk) {
      bf16x8 af[4], bfr[4];
      #pragma unroll
      for (int i = 0; i < 4; ++i)
        af[i] = *reinterpret_cast<const bf16x8*>(&Al[(wr * 64 + i * 16 + lr) * 64 + kk * 32 + lg * 8]);
      #pragma unroll
      for (int j = 0; j < 4; ++j)
        bfr[j] = *reinterpret_cast<const bf16x8*>(&Bl[(wc * 64 + j * 16 + lr) * 64 + kk * 32 + lg * 8]);
      #pragma unroll
      for (int i = 0; i < 4; ++i)
        #pragma unroll
        for (int j = 0; j < 4; ++j)
          acc[i][j] = __builtin_amdgcn_mfma_f32_16x16x32_bf16(af[i], bfr[j], acc[i][j], 0, 0, 0);
    }
    __builtin_amdgcn_s_setprio(0);
  }

  #pragma unroll
  for (int j = 0; j < 4; ++j) {
    int n = ntile + wc * 64 + j * 16 + lr;   // 0..3071 (sec uniform per block)
    float bv = bias[n];
    int sec = n >> 10;
    int ch = n & 1023;
    int h = ch >> 6, d = ch & 63;
    if (sec == 2) {
      // v transposed: [bh][d][t], pack 4 consecutive t per lane
      #pragma unroll
      for (int i = 0; i < 4; ++i) {
        int t0g = mtile + wr * 64 + i * 16 + lg * 4;
        int bb = t0g >> 11, t = t0g & 2047;
        short4 pk;
        pk.x = f2bf(acc[i][j][0] + bv);
        pk.y = f2bf(acc[i][j][1] + bv);
        pk.z = f2bf(acc[i][j][2] + bv);
        pk.w = f2bf(acc[i][j][3] + bv);
        *reinterpret_cast<short4*>(&vt[((size_t)(bb * 16 + h) * 64 + d) * 2048 + t]) = pk;
      }
    } else {
      short* dst = (sec == 0) ? qo : ko;
      float sc = (sec == 0) ? 0.125f : 1.0f;
      #pragma unroll
      for (int i = 0; i < 4; ++i) {
        #pragma unroll
        for (int r = 0; r < 4; ++r) {
          int m = mtile + wr * 64 + i * 16 + lg * 4 + r;
          int bb = m >> 11, t = m & 2047;
          dst[(size_t)((bb * 16 + h) * 2048 + t) * 64 + d] = f2bf((acc[i][j][r] + bv) * sc);
        }
      }
    }
  }
}

// ---- flash attention, causal-balanced pairing ----
// q,k: [BH32][T2048][D64]; vt: [BH32][D64][T2048]; y: [B][T][C] bf16
// block (j,bh): q-tiles j and 31-j; kv tiles 0..31-j; lo tile active for kv<=j
__global__ __launch_bounds__(256) void attn_kernel(const short* __restrict__ q,
                                                   const short* __restrict__ k,
                                                   const short* __restrict__ vt,
                                                   short* __restrict__ y) {
  __shared__ short Ks[2][4096];    // [ck 0..7][kvrow 0..63][8]
  __shared__ short Vs[2][4096];    // [ck 0..7][drow 0..63][8]  (V^T tile)
  __shared__ short Plds[4][16][72];
  const int tid = threadIdx.x;
  const int w = tid >> 6, l = tid & 63, lr = l & 15, lg = l >> 4;
  // XCD swizzle: keep all 16 j-blocks of ~4 bh on one XCD's L2
  int fid = blockIdx.y * 16 + blockIdx.x;
  int vid = (fid & 7) * 64 + (fid >> 3);
  const int bh = vid >> 4;
  const int j = vid & 15;
  const int hi = 31 - j;
  const int nkv = 32 - j;
  const short* qb = q + (size_t)bh * 131072;
  const short* kb = k + (size_t)bh * 131072;
  const short* vtb = vt + (size_t)bh * 131072;

  bf16x8 qhi[2], qlo[2];
  {
    int r1 = hi * 64 + w * 16 + lr, r2 = j * 64 + w * 16 + lr;
    #pragma unroll
    for (int kk = 0; kk < 2; ++kk) {
      qhi[kk] = *reinterpret_cast<const bf16x8*>(&qb[(size_t)r1 * 64 + kk * 32 + lg * 8]);
      qlo[kk] = *reinterpret_cast<const bf16x8*>(&qb[(size_t)r2 * 64 + kk * 32 + lg * 8]);
    }
  }

  const f32x4 zero4 = {0.f, 0.f, 0.f, 0.f};
  float mh[4], lh[4], ml[4], llo[4];
  f32x4 yh[4], yl[4];
  #pragma unroll
  for (int r = 0; r < 4; ++r) { mh[r] = -1e30f; lh[r] = 0.f; ml[r] = -1e30f; llo[r] = 0.f; }
  #pragma unroll
  for (int gd = 0; gd < 4; ++gd) { yh[gd] = zero4; yl[gd] = zero4; }

  const int srow = tid >> 3, sck = tid & 7;
  uint4 kreg[2], vreg[2];

#define LOADT(IT) do {                                                              \
    int kv0_ = (IT) * 64;                                                           \
    _Pragma("unroll")                                                               \
    for (int c = 0; c < 2; ++c) {                                                   \
      int row_ = srow + c * 32;                                                     \
      kreg[c] = *reinterpret_cast<const uint4*>(&kb[(size_t)(kv0_ + row_) * 64 + sck * 8]); \
      vreg[c] = *reinterpret_cast<const uint4*>(&vtb[(size_t)row_ * 2048 + kv0_ + sck * 8]); \
    }                                                                               \
  } while (0)

#define STORET(BUF) do {                                                            \
    _Pragma("unroll")                                                               \
    for (int c = 0; c < 2; ++c) {                                                   \
      int row_ = srow + c * 32;                                                     \
      *reinterpret_cast<uint4*>(&Ks[BUF][(sck * 64 + row_) * 8]) = kreg[c];         \
      *reinterpret_cast<uint4*>(&Vs[BUF][(sck * 64 + row_) * 8]) = vreg[c];         \
    }                                                                               \
  } while (0)

#define PROC(QA, MI, LI, YACC, QT, IT, BUF) do {                                    \
    f32x4 s_[4];                                                                    \
    _Pragma("unroll") for (int g = 0; g < 4; ++g) s_[g] = zero4;                    \
    __builtin_amdgcn_s_setprio(1);                                                  \
    _Pragma("unroll")                                                               \
    for (int g = 0; g < 4; ++g)                                                     \
      _Pragma("unroll")                                                             \
      for (int kk = 0; kk < 2; ++kk) {                                              \
        bf16x8 kf_ = *reinterpret_cast<const bf16x8*>(&Ks[BUF][((kk * 4 + lg) * 64 + g * 16 + lr) * 8]); \
        s_[g] = __builtin_amdgcn_mfma_f32_16x16x32_bf16((QA)[kk], kf_, s_[g], 0, 0, 0); \
      }                                                                             \
    __builtin_amdgcn_s_setprio(0);                                                  \
    if ((IT) == (QT)) {                                                             \
      _Pragma("unroll")                                                             \
      for (int g = 0; g < 4; ++g)                                                   \
        _Pragma("unroll")                                                           \
        for (int r = 0; r < 4; ++r) {                                               \
          int col_ = (IT) * 64 + g * 16 + lr;                                       \
          int row_ = (QT) * 64 + w * 16 + lg * 4 + r;                               \
          if (col_ > row_) s_[g][r] = -1e30f;                                       \
        }                                                                           \
    }                                                                               \
    _Pragma("unroll")                                                               \
    for (int r = 0; r < 4; ++r) {                                                   \
      float tm_ = fmaxf(fmaxf(s_[0][r], s_[1][r]), fmaxf(s_[2][r], s_[3][r]));      \
      tm_ = fmaxf(tm_, __shfl_xor(tm_, 1));                                         \
      tm_ = fmaxf(tm_, __shfl_xor(tm_, 2));                                         \
      tm_ = fmaxf(tm_, __shfl_xor(tm_, 4));                                         \
      tm_ = fmaxf(tm_, __shfl_xor(tm_, 8));                                         \
      float mnew_ = fmaxf((MI)[r], tm_);                                            \
      float scl_ = __expf((MI)[r] - mnew_);                                         \
      (MI)[r] = mnew_;                                                              \
      float rsum_ = 0.f;                                                            \
      _Pragma("unroll")                                                             \
      for (int g = 0; g < 4; ++g) {                                                 \
        float p_ = __expf(s_[g][r] - mnew_);                                        \
        s_[g][r] = p_;                                                              \
        rsum_ += p_;                                                                \
      }                                                                             \
      rsum_ += __shfl_xor(rsum_, 1);                                                \
      rsum_ += __shfl_xor(rsum_, 2);                                                \
      rsum_ += __shfl_xor(rsum_, 4);                                                \
      rsum_ += __shfl_xor(rsum_, 8);                                                \
      (LI)[r] = (LI)[r] * scl_ + rsum_;                                             \
      _Pragma("unroll")                                                             \
      for (int gd = 0; gd < 4; ++gd) (YACC)[gd][r] *= scl_;                         \
    }                                                                               \
    _Pragma("unroll")                                                               \
    for (int g = 0; g < 4; ++g)                                                     \
      _Pragma("unroll")                                                             \
      for (int r = 0; r < 4; ++r)                                                   \
        Plds[w][lg * 4 + r][g * 16 + lr] = f2bf(s_[g][r]);                          \
    bf16x8 pa_[2];                                                                  \
    _Pragma("unroll")                                                               \
    for (int kk = 0; kk < 2; ++kk)                                                  \
      pa_[kk] = *reinterpret_cast<const bf16x8*>(&Plds[w][lr][kk * 32 + lg * 8]);   \
    __builtin_amdgcn_s_setprio(1);                                                  \
    _Pragma("unroll")                                                               \
    for (int gd = 0; gd < 4; ++gd)                                                  \
      _Pragma("unroll")                                                             \
      for (int kk = 0; kk < 2; ++kk) {                                              \
        bf16x8 vf_ = *reinterpret_cast<const bf16x8*>(&Vs[BUF][((kk * 4 + lg) * 64 + gd * 16 + lr) * 8]); \
        (YACC)[gd] = __builtin_amdgcn_mfma_f32_16x16x32_bf16(pa_[kk], vf_, (YACC)[gd], 0, 0, 0); \
      }                                                                             \
    __builtin_amdgcn_s_setprio(0);                                                  \
  } while (0)

  LOADT(0);
  STORET(0);
  for (int it = 0; it < nkv; ++it) {
    __syncthreads();
    int buf = it & 1;
    bool pre = (it + 1 < nkv);
    if (pre) LOADT(it + 1);            // issue next-tile global loads early
    PROC(qhi, mh, lh, yh, hi, it, buf);
    if (it <= j) PROC(qlo, ml, llo, yl, j, it, buf);
    if (pre) STORET(buf ^ 1);          // write-late into the other buffer
  }

  int b_ = bh >> 4, h_ = bh & 15;
#define WOUT(LI, YACC, QT) do {                                                     \
    float inv_[4];                                                                  \
    _Pragma("unroll") for (int r = 0; r < 4; ++r) inv_[r] = 1.0f / (LI)[r];         \
    _Pragma("unroll")                                                               \
    for (int gd = 0; gd < 4; ++gd)                                                  \
      _Pragma("unroll")                                                             \
      for (int r = 0; r < 4; ++r) {                                                 \
        int row_ = (QT) * 64 + w * 16 + lg * 4 + r;                                 \
        y[(size_t)(b_ * 2048 + row_) * 1024 + h_ * 64 + gd * 16 + lr] =             \
            f2bf((YACC)[gd][r] * inv_[r]);                                          \
      }                                                                             \
  } while (0)

  WOUT(lh, yh, hi);
  WOUT(llo, yl, j);
#undef LOADT
#undef STORET
#undef PROC
#undef WOUT
}

// ---- GEMM3: out fp32 = y_bf[4096][1024] * Wproj_t[1024][1024]^T + bproj ----
__global__ __launch_bounds__(256) void gemm_proj(const short* __restrict__ A,
                                                 const short* __restrict__ Bt,
                                                 const float* __restrict__ bias,
                                                 float* __restrict__ out) {
  const int K = 1024;
  __shared__ short Al[8192];
  __shared__ short Bl[8192];
  int tid = threadIdx.x;
  int mtile = blockIdx.y * 128, ntile = blockIdx.x * 128;
  int w = tid >> 6, l = tid & 63;
  int wr = w >> 1, wc = w & 1;
  int lr = l & 15, lg = l >> 4;

  f32x4 zero4 = {0.f, 0.f, 0.f, 0.f};
  f32x4 acc[4][4];
  #pragma unroll
  for (int i = 0; i < 4; ++i)
    #pragma unroll
    for (int j = 0; j < 4; ++j) acc[i][j] = zero4;

  for (int k0 = 0; k0 < K; k0 += 64) {
    __syncthreads();
    #pragma unroll
    for (int c = 0; c < 4; ++c) {
      int idx = tid + c * 256;
      int row = idx >> 3, kc = idx & 7;
      gl_lds16(&A[(size_t)(mtile + row) * K + k0 + kc * 8], &Al[idx * 8]);
      gl_lds16(&Bt[(size_t)(ntile + row) * K + k0 + kc * 8], &Bl[idx * 8]);
    }
    __syncthreads();
    __builtin_amdgcn_s_setprio(1);
    #pragma unroll
    for (int kk = 0; kk < 2; ++kk) {
      bf16x8 af[4], bfr[4];
      #pragma unroll
      for (int i = 0; i < 4; ++i)
        af[i] = *reinterpret_cast<const bf16x8*>(&Al[(wr * 64 + i * 16 + lr) * 64 + kk * 32 + lg * 8]);
      #pragma unroll
      for (int j = 0; j < 4; ++j)
        bfr[j] = *reinterpret_cast<const bf16x8*>(&Bl[(wc * 64 + j * 16 + lr) * 64 + kk * 32 + lg * 8]);
      #pragma unroll
      for (int i = 0; i < 4; ++i)
        #pragma unroll
        for (int j = 0; j < 4; ++j)
          acc[i][j] = __builtin_amdgcn_mfma_f32_16x16x32_bf16(af[i], bfr[j], acc[i][j], 0, 0, 0);
    }
    __builtin_amdgcn_s_setprio(0);
  }

  #pragma unroll
  for (int j = 0; j < 4; ++j) {
    int n = ntile + wc * 64 + j * 16 + lr;
    float bv = bias[n];
    #pragma unroll
    for (int i = 0; i < 4; ++i) {
      #pragma unroll
      for (int r = 0; r < 4; ++r) {
        int m = mtile + wr * 64 + i * 16 + lg * 4 + r;
        out[(size_t)m * 1024 + n] = acc[i][j][r] + bv;
      }
    }
  }
}

extern "C" void kernel_launch(void* const* d_in, const int* in_sizes, int n_in,
                              void* d_out, int out_size, void* d_ws, size_t ws_size,
                              hipStream_t stream) {
  const float* x     = (const float*)d_in[0];
  const float* Wqkv  = (const float*)d_in[1];
  const float* bqkv  = (const float*)d_in[2];
  const float* Wproj = (const float*)d_in[3];
  const float* bproj = (const float*)d_in[4];
  float* out = (float*)d_out;

  const size_t M4 = 4096ull * 1024ull;
  short* ws = (short*)d_ws;
  short* x_bf    = ws;
  short* wqkv_t  = ws + M4;
  short* wproj_t = ws + M4 + 3ull * 1024 * 1024;
  short* qb      = wproj_t + 1024ull * 1024;
  short* kb      = qb + M4;
  short* vtb     = kb + M4;     // [bh][64][2048] transposed V
  short* yb      = x_bf;        // alias: x_bf dead after gemm_qkv

  cast_x_kernel<<<4096, 256, 0, stream>>>(x, x_bf, (int)(M4 / 4));
  transpose_cast<<<dim3(48, 16), 256, 0, stream>>>(Wqkv, wqkv_t, 1024, 3072);
  transpose_cast<<<dim3(16, 16), 256, 0, stream>>>(Wproj, wproj_t, 1024, 1024);
  gemm_qkv<<<dim3(24, 32), 256, 0, stream>>>(x_bf, wqkv_t, bqkv, qb, kb, vtb);
  attn_kernel<<<dim3(16, 32), 256, 0, stream>>>(qb, kb, vtb, yb);
  gemm_proj<<<dim3(8, 32), 256, 0, stream>>>(yb, wproj_t, bproj, out);
}

// Round 3
// 183.513 us; speedup vs baseline: 1.0923x; 1.0923x over previous
//
#include <hip/hip_runtime.h>

// ---- types ----
typedef __bf16 bf16x8 __attribute__((ext_vector_type(8)));
typedef float  f32x4  __attribute__((ext_vector_type(4)));

__device__ __forceinline__ short f2bf(float f) {
  union { float f; unsigned u; } v; v.f = f;
  unsigned r = v.u + 0x7fffu + ((v.u >> 16) & 1u);
  return (short)(r >> 16);
}

// async global->LDS (16B per lane); LDS dest must be wave-uniform base + lane*16
__device__ __forceinline__ void gl_lds16(const short* g, short* l) {
  __builtin_amdgcn_global_load_lds((const __attribute__((address_space(1))) void*)g,
                                   (__attribute__((address_space(3))) void*)l, 16, 0, 0);
}

// ---- cast x fp32 -> bf16 (vectorized) ----
__global__ __launch_bounds__(256) void cast_x_kernel(const float* __restrict__ in,
                                                     short* __restrict__ out, int n4) {
  int i = blockIdx.x * 256 + threadIdx.x;
  if (i >= n4) return;
  float4 f = reinterpret_cast<const float4*>(in)[i];
  short4 o;
  o.x = f2bf(f.x); o.y = f2bf(f.y); o.z = f2bf(f.z); o.w = f2bf(f.w);
  reinterpret_cast<short4*>(out)[i] = o;
}

// ---- transpose + cast: in[R][Cc] fp32 -> out[Cc][R] bf16 ----
__global__ __launch_bounds__(256) void transpose_cast(const float* __restrict__ in,
                                                      short* __restrict__ out, int R, int Cc) {
  __shared__ short tile[64][65];
  int bx = blockIdx.x * 64;
  int by = blockIdx.y * 64;
  int tx = threadIdx.x & 63, ty = threadIdx.x >> 6;
  #pragma unroll
  for (int i = ty; i < 64; i += 4)
    tile[i][tx] = f2bf(in[(size_t)(by + i) * Cc + bx + tx]);
  __syncthreads();
  #pragma unroll
  for (int i = ty; i < 64; i += 4)
    out[(size_t)(bx + i) * R + by + tx] = tile[tx][i];
}

// ---- GEMM1: qkv = x_bf[4096][1024] * Wqkv_t[3072][1024]^T + bqkv
//      q,k -> [B2][H16][T2048][D64] bf16 (q scaled 0.125); v -> TRANSPOSED [BH][D64][T2048]
__global__ __launch_bounds__(256) void gemm_qkv(const short* __restrict__ A,
                                                const short* __restrict__ Bt,
                                                const float* __restrict__ bias,
                                                short* __restrict__ qo,
                                                short* __restrict__ ko,
                                                short* __restrict__ vt) {
  const int K = 1024;
  __shared__ short Al[8192];   // linear [128][64]
  __shared__ short Bl[8192];
  int tid = threadIdx.x;
  int mtile = blockIdx.y * 128, ntile = blockIdx.x * 128;
  int w = tid >> 6, l = tid & 63;
  int wr = w >> 1, wc = w & 1;
  int lr = l & 15, lg = l >> 4;

  f32x4 zero4 = {0.f, 0.f, 0.f, 0.f};
  f32x4 acc[4][4];
  #pragma unroll
  for (int i = 0; i < 4; ++i)
    #pragma unroll
    for (int j = 0; j < 4; ++j) acc[i][j] = zero4;

  for (int k0 = 0; k0 < K; k0 += 64) {
    __syncthreads();
    #pragma unroll
    for (int c = 0; c < 4; ++c) {
      int idx = tid + c * 256;
      int row = idx >> 3, kc = idx & 7;
      gl_lds16(&A[(size_t)(mtile + row) * K + k0 + kc * 8], &Al[idx * 8]);
      gl_lds16(&Bt[(size_t)(ntile + row) * K + k0 + kc * 8], &Bl[idx * 8]);
    }
    __syncthreads();
    __builtin_amdgcn_s_setprio(1);
    #pragma unroll
    for (int kk = 0; kk < 2; ++kk) {
      bf16x8 af[4], bfr[4];
      #pragma unroll
      for (int i = 0; i < 4; ++i)
        af[i] = *reinterpret_cast<const bf16x8*>(&Al[(wr * 64 + i * 16 + lr) * 64 + kk * 32 + lg * 8]);
      #pragma unroll
      for (int j = 0; j < 4; ++j)
        bfr[j] = *reinterpret_cast<const bf16x8*>(&Bl[(wc * 64 + j * 16 + lr) * 64 + kk * 32 + lg * 8]);
      #pragma unroll
      for (int i = 0; i < 4; ++i)
        #pragma unroll
        for (int j = 0; j < 4; ++j)
          acc[i][j] = __builtin_amdgcn_mfma_f32_16x16x32_bf16(af[i], bfr[j], acc[i][j], 0, 0, 0);
    }
    __builtin_amdgcn_s_setprio(0);
  }

  #pragma unroll
  for (int j = 0; j < 4; ++j) {
    int n = ntile + wc * 64 + j * 16 + lr;   // 0..3071 (sec uniform per block)
    float bv = bias[n];
    int sec = n >> 10;
    int ch = n & 1023;
    int h = ch >> 6, d = ch & 63;
    if (sec == 2) {
      // v transposed: [bh][d][t], pack 4 consecutive t per lane
      #pragma unroll
      for (int i = 0; i < 4; ++i) {
        int t0g = mtile + wr * 64 + i * 16 + lg * 4;
        int bb = t0g >> 11, t = t0g & 2047;
        short4 pk;
        pk.x = f2bf(acc[i][j][0] + bv);
        pk.y = f2bf(acc[i][j][1] + bv);
        pk.z = f2bf(acc[i][j][2] + bv);
        pk.w = f2bf(acc[i][j][3] + bv);
        *reinterpret_cast<short4*>(&vt[((size_t)(bb * 16 + h) * 64 + d) * 2048 + t]) = pk;
      }
    } else {
      short* dst = (sec == 0) ? qo : ko;
      float sc = (sec == 0) ? 0.125f : 1.0f;
      #pragma unroll
      for (int i = 0; i < 4; ++i) {
        #pragma unroll
        for (int r = 0; r < 4; ++r) {
          int m = mtile + wr * 64 + i * 16 + lg * 4 + r;
          int bb = m >> 11, t = m & 2047;
          dst[(size_t)((bb * 16 + h) * 2048 + t) * 64 + d] = f2bf((acc[i][j][r] + bv) * sc);
        }
      }
    }
  }
}

// ---- flash attention v3: swapped-operand MFMA, row-local softmax, swizzled LDS,
//      KVBLK=128 (2x 64-subtiles per stage), causal-balanced pairing ----
// q,k: [BH32][T2048][D64]; vt: [BH32][D64][T2048]; y: [B][T][C] bf16
__global__ __launch_bounds__(256) void attn_kernel(const short* __restrict__ q,
                                                   const short* __restrict__ k,
                                                   const short* __restrict__ vt,
                                                   short* __restrict__ y) {
  __shared__ short Ks[2][2][4096];   // [buf][subtile][row 0..63][slot^(row&7)][8]
  __shared__ short Vs[2][2][4096];   // [buf][subtile][d   0..63][slot^(d&7)][8]
  __shared__ short Plds[4][16][80];  // per-wave P rows (stride 80 -> 16B-aligned reads)
  const int tid = threadIdx.x;
  const int w = tid >> 6, l = tid & 63, lr = l & 15, lg = l >> 4;
  // XCD swizzle: all 16 j-blocks of 4 bh per XCD (K/V L2-resident)
  int fid = blockIdx.y * 16 + blockIdx.x;
  int vid = (fid & 7) * 64 + (fid >> 3);
  const int bh = vid >> 4;
  const int j = vid & 15;
  const int hi = 31 - j;
  const int niter = (33 - j) >> 1;      // ceil((32-j)/2) 128-wide stages
  const short* qb = q + (size_t)bh * 131072;
  const short* kb = k + (size_t)bh * 131072;
  const short* vtb = vt + (size_t)bh * 131072;

  bf16x8 qhi[2], qlo[2];
  {
    int r1 = hi * 64 + w * 16 + lr, r2 = j * 64 + w * 16 + lr;
    #pragma unroll
    for (int kk = 0; kk < 2; ++kk) {
      qhi[kk] = *reinterpret_cast<const bf16x8*>(&qb[(size_t)r1 * 64 + kk * 32 + lg * 8]);
      qlo[kk] = *reinterpret_cast<const bf16x8*>(&qb[(size_t)r2 * 64 + kk * 32 + lg * 8]);
    }
  }

  const f32x4 zero4 = {0.f, 0.f, 0.f, 0.f};
  float mh = -1e30f, lh = 0.f, ml = -1e30f, llo = 0.f;
  f32x4 yh[4], yl[4];
  #pragma unroll
  for (int gd = 0; gd < 4; ++gd) { yh[gd] = zero4; yl[gd] = zero4; }

  // staging decomposition (per thread: 4 K-chunks + 4 V-chunks of 16B)
  const int krow = tid >> 1;            // 0..127
  const int ksub = krow >> 6, krow6 = krow & 63;
  const int vd = tid >> 2;              // 0..63
  uint4 kreg[4], vreg[4];

#define LOADT(IT) do {                                                               \
    int kv0_ = (IT) * 128;                                                           \
    _Pragma("unroll")                                                                \
    for (int c = 0; c < 4; ++c) {                                                    \
      kreg[c] = *reinterpret_cast<const uint4*>(&kb[(size_t)(kv0_ + krow) * 64 + ((tid & 1) * 4 + c) * 8]); \
      vreg[c] = *reinterpret_cast<const uint4*>(&vtb[(size_t)vd * 2048 + kv0_ + ((tid & 3) * 4 + c) * 8]);  \
    }                                                                                \
  } while (0)

#define STORET(BUF) do {                                                             \
    _Pragma("unroll")                                                                \
    for (int c = 0; c < 4; ++c) {                                                    \
      int ks_ = (tid & 1) * 4 + c;                                                   \
      *reinterpret_cast<uint4*>(&Ks[BUF][ksub][krow6 * 64 + (ks_ ^ (krow6 & 7)) * 8]) = kreg[c]; \
      int ch_ = (tid & 3) * 4 + c;                                                   \
      *reinterpret_cast<uint4*>(&Vs[BUF][ch_ >> 3][vd * 64 + ((ch_ & 7) ^ (vd & 7)) * 8]) = vreg[c]; \
    }                                                                                \
  } while (0)

  // One 64-wide subtile: S^T = mfma(K,Q) -> lane owns q-row lr; row-local softmax;
  // P repacked via per-wave LDS; Y^T += mfma(V,P).
#define PROC(QA, MI, LI, YT, QT, T64, BUF, SUB) do {                                 \
    f32x4 s_[4];                                                                     \
    _Pragma("unroll") for (int g = 0; g < 4; ++g) s_[g] = zero4;                     \
    __builtin_amdgcn_s_setprio(1);                                                   \
    _Pragma("unroll")                                                                \
    for (int g = 0; g < 4; ++g)                                                      \
      _Pragma("unroll")                                                              \
      for (int kk = 0; kk < 2; ++kk) {                                               \
        bf16x8 kf_ = *reinterpret_cast<const bf16x8*>(                               \
            &Ks[BUF][SUB][(g * 16 + lr) * 64 + (((kk * 4 + lg) ^ (lr & 7)) * 8)]);   \
        s_[g] = __builtin_amdgcn_mfma_f32_16x16x32_bf16(kf_, (QA)[kk], s_[g], 0, 0, 0); \
      }                                                                              \
    __builtin_amdgcn_s_setprio(0);                                                   \
    if ((T64) == (QT)) {                                                             \
      _Pragma("unroll")                                                              \
      for (int g = 0; g < 4; ++g)                                                    \
        _Pragma("unroll")                                                            \
        for (int r = 0; r < 4; ++r)                                                  \
          if (g * 16 + lg * 4 + r > w * 16 + lr) s_[g][r] = -1e30f;                  \
    }                                                                                \
    float t0_ = fmaxf(fmaxf(s_[0][0], s_[0][1]), fmaxf(s_[0][2], s_[0][3]));         \
    float t1_ = fmaxf(fmaxf(s_[1][0], s_[1][1]), fmaxf(s_[1][2], s_[1][3]));         \
    float t2_ = fmaxf(fmaxf(s_[2][0], s_[2][1]), fmaxf(s_[2][2], s_[2][3]));         \
    float t3_ = fmaxf(fmaxf(s_[3][0], s_[3][1]), fmaxf(s_[3][2], s_[3][3]));         \
    float tm_ = fmaxf(fmaxf(t0_, t1_), fmaxf(t2_, t3_));                             \
    tm_ = fmaxf(tm_, __shfl_xor(tm_, 16));                                           \
    tm_ = fmaxf(tm_, __shfl_xor(tm_, 32));                                           \
    float mnew_ = fmaxf((MI), tm_);                                                  \
    float scl_ = __expf((MI) - mnew_);                                               \
    (MI) = mnew_;                                                                    \
    float rs_ = 0.f;                                                                 \
    _Pragma("unroll")                                                                \
    for (int g = 0; g < 4; ++g)                                                      \
      _Pragma("unroll")                                                              \
      for (int r = 0; r < 4; ++r) {                                                  \
        float p_ = __expf(s_[g][r] - mnew_);                                         \
        s_[g][r] = p_;                                                               \
        rs_ += p_;                                                                   \
      }                                                                              \
    rs_ += __shfl_xor(rs_, 16);                                                      \
    rs_ += __shfl_xor(rs_, 32);                                                      \
    (LI) = (LI) * scl_ + rs_;                                                        \
    _Pragma("unroll")                                                                \
    for (int gd = 0; gd < 4; ++gd)                                                   \
      _Pragma("unroll")                                                              \
      for (int r = 0; r < 4; ++r) (YT)[gd][r] *= scl_;                               \
    _Pragma("unroll")                                                                \
    for (int g = 0; g < 4; ++g) {                                                    \
      uint2 pk_;                                                                     \
      pk_.x = (unsigned)(unsigned short)f2bf(s_[g][0]) |                             \
              ((unsigned)(unsigned short)f2bf(s_[g][1]) << 16);                      \
      pk_.y = (unsigned)(unsigned short)f2bf(s_[g][2]) |                             \
              ((unsigned)(unsigned short)f2bf(s_[g][3]) << 16);                      \
      *reinterpret_cast<uint2*>(&Plds[w][lr][g * 16 + lg * 4]) = pk_;                \
    }                                                                                \
    bf16x8 pa_[2];                                                                   \
    _Pragma("unroll")                                                                \
    for (int kk = 0; kk < 2; ++kk)                                                   \
      pa_[kk] = *reinterpret_cast<const bf16x8*>(&Plds[w][lr][kk * 32 + lg * 8]);    \
    __builtin_amdgcn_s_setprio(1);                                                   \
    _Pragma("unroll")                                                                \
    for (int gd = 0; gd < 4; ++gd)                                                   \
      _Pragma("unroll")                                                              \
      for (int kk = 0; kk < 2; ++kk) {                                               \
        bf16x8 vf_ = *reinterpret_cast<const bf16x8*>(                               \
            &Vs[BUF][SUB][(gd * 16 + lr) * 64 + (((kk * 4 + lg) ^ (lr & 7)) * 8)]);  \
        (YT)[gd] = __builtin_amdgcn_mfma_f32_16x16x32_bf16(vf_, pa_[kk], (YT)[gd], 0, 0, 0); \
      }                                                                              \
    __builtin_amdgcn_s_setprio(0);                                                   \
  } while (0)

  LOADT(0);
  STORET(0);
  for (int it = 0; it < niter; ++it) {
    __syncthreads();
    int buf = it & 1;
    bool pre = (it + 1 < niter);
    if (pre) LOADT(it + 1);
    int t0 = it * 2, t1 = it * 2 + 1;
    PROC(qhi, mh, lh, yh, hi, t0, buf, 0);
    if (t1 <= hi) PROC(qhi, mh, lh, yh, hi, t1, buf, 1);
    if (t0 <= j) PROC(qlo, ml, llo, yl, j, t0, buf, 0);
    if (t1 <= j) PROC(qlo, ml, llo, yl, j, t1, buf, 1);
    if (pre) STORET(buf ^ 1);
  }

  int b_ = bh >> 4, h_ = bh & 15;
#define WOUT(LI, YT, QT) do {                                                        \
    float inv_ = 1.0f / (LI);                                                        \
    int qrow_ = (QT) * 64 + w * 16 + lr;                                             \
    _Pragma("unroll")                                                                \
    for (int gd = 0; gd < 4; ++gd) {                                                 \
      short4 pk_;                                                                    \
      pk_.x = f2bf((YT)[gd][0] * inv_);                                              \
      pk_.y = f2bf((YT)[gd][1] * inv_);                                              \
      pk_.z = f2bf((YT)[gd][2] * inv_);                                              \
      pk_.w = f2bf((YT)[gd][3] * inv_);                                              \
      *reinterpret_cast<short4*>(                                                    \
          &y[(size_t)(b_ * 2048 + qrow_) * 1024 + h_ * 64 + gd * 16 + lg * 4]) = pk_;\
    }                                                                                \
  } while (0)

  WOUT(lh, yh, hi);
  WOUT(llo, yl, j);
#undef LOADT
#undef STORET
#undef PROC
#undef WOUT
}

// ---- GEMM3: out fp32 = y_bf[4096][1024] * Wproj_t[1024][1024]^T + bproj ----
__global__ __launch_bounds__(256) void gemm_proj(const short* __restrict__ A,
                                                 const short* __restrict__ Bt,
                                                 const float* __restrict__ bias,
                                                 float* __restrict__ out) {
  const int K = 1024;
  __shared__ short Al[8192];
  __shared__ short Bl[8192];
  int tid = threadIdx.x;
  int mtile = blockIdx.y * 128, ntile = blockIdx.x * 128;
  int w = tid >> 6, l = tid & 63;
  int wr = w >> 1, wc = w & 1;
  int lr = l & 15, lg = l >> 4;

  f32x4 zero4 = {0.f, 0.f, 0.f, 0.f};
  f32x4 acc[4][4];
  #pragma unroll
  for (int i = 0; i < 4; ++i)
    #pragma unroll
    for (int j = 0; j < 4; ++j) acc[i][j] = zero4;

  for (int k0 = 0; k0 < K; k0 += 64) {
    __syncthreads();
    #pragma unroll
    for (int c = 0; c < 4; ++c) {
      int idx = tid + c * 256;
      int row = idx >> 3, kc = idx & 7;
      gl_lds16(&A[(size_t)(mtile + row) * K + k0 + kc * 8], &Al[idx * 8]);
      gl_lds16(&Bt[(size_t)(ntile + row) * K + k0 + kc * 8], &Bl[idx * 8]);
    }
    __syncthreads();
    __builtin_amdgcn_s_setprio(1);
    #pragma unroll
    for (int kk = 0; kk < 2; ++kk) {
      bf16x8 af[4], bfr[4];
      #pragma unroll
      for (int i = 0; i < 4; ++i)
        af[i] = *reinterpret_cast<const bf16x8*>(&Al[(wr * 64 + i * 16 + lr) * 64 + kk * 32 + lg * 8]);
      #pragma unroll
      for (int j = 0; j < 4; ++j)
        bfr[j] = *reinterpret_cast<const bf16x8*>(&Bl[(wc * 64 + j * 16 + lr) * 64 + kk * 32 + lg * 8]);
      #pragma unroll
      for (int i = 0; i < 4; ++i)
        #pragma unroll
        for (int j = 0; j < 4; ++j)
          acc[i][j] = __builtin_amdgcn_mfma_f32_16x16x32_bf16(af[i], bfr[j], acc[i][j], 0, 0, 0);
    }
    __builtin_amdgcn_s_setprio(0);
  }

  #pragma unroll
  for (int j = 0; j < 4; ++j) {
    int n = ntile + wc * 64 + j * 16 + lr;
    float bv = bias[n];
    #pragma unroll
    for (int i = 0; i < 4; ++i) {
      #pragma unroll
      for (int r = 0; r < 4; ++r) {
        int m = mtile + wr * 64 + i * 16 + lg * 4 + r;
        out[(size_t)m * 1024 + n] = acc[i][j][r] + bv;
      }
    }
  }
}

extern "C" void kernel_launch(void* const* d_in, const int* in_sizes, int n_in,
                              void* d_out, int out_size, void* d_ws, size_t ws_size,
                              hipStream_t stream) {
  const float* x     = (const float*)d_in[0];
  const float* Wqkv  = (const float*)d_in[1];
  const float* bqkv  = (const float*)d_in[2];
  const float* Wproj = (const float*)d_in[3];
  const float* bproj = (const float*)d_in[4];
  float* out = (float*)d_out;

  const size_t M4 = 4096ull * 1024ull;
  short* ws = (short*)d_ws;
  short* x_bf    = ws;
  short* wqkv_t  = ws + M4;
  short* wproj_t = ws + M4 + 3ull * 1024 * 1024;
  short* qb      = wproj_t + 1024ull * 1024;
  short* kb      = qb + M4;
  short* vtb     = kb + M4;     // [bh][64][2048] transposed V
  short* yb      = x_bf;        // alias: x_bf dead after gemm_qkv

  cast_x_kernel<<<4096, 256, 0, stream>>>(x, x_bf, (int)(M4 / 4));
  transpose_cast<<<dim3(48, 16), 256, 0, stream>>>(Wqkv, wqkv_t, 1024, 3072);
  transpose_cast<<<dim3(16, 16), 256, 0, stream>>>(Wproj, wproj_t, 1024, 1024);
  gemm_qkv<<<dim3(24, 32), 256, 0, stream>>>(x_bf, wqkv_t, bqkv, qb, kb, vtb);
  attn_kernel<<<dim3(16, 32), 256, 0, stream>>>(qb, kb, vtb, yb);
  gemm_proj<<<dim3(8, 32), 256, 0, stream>>>(yb, wproj_t, bproj, out);
}